// Round 14
// baseline (4781.334 us; speedup 1.0000x reference)
//
#include <hip/hip_runtime.h>
#include <hip/hip_bf16.h>
#include <stdint.h>

#define IGNORE_INDEX (-100)

constexpr int kB2 = 8, kT = 1024, kH = 2048, kV = 32000;
constexpr int kM = kB2 * kT;           // 8192 token rows
constexpr int BM = 256, BN = 256, BK = 128;   // fp8: 128-B rows
constexpr int NSPLIT = 125;            // vocab splits (1 N-tile each)
constexpr int MBLKS = kM / BM;         // 32 row blocks
constexpr int KT = kH / BK;            // 16 K-tiles
constexpr int NWG = NSPLIT * MBLKS;    // 4000 workgroups

typedef int   i32x4  __attribute__((ext_vector_type(4)));
typedef int   i32x8  __attribute__((ext_vector_type(8)));
typedef float f32x4  __attribute__((ext_vector_type(4)));

// ---------------- cast fp32 -> fp8 e4m3 (OCP), optional pre-scale ----------------
__global__ void cast_to_fp8(const float* __restrict__ src, uint2* __restrict__ dst,
                            int n8, float scale) {
  int idx = blockIdx.x * blockDim.x + threadIdx.x;
  int stride = gridDim.x * blockDim.x;
  const float4* s = (const float4*)src;
  for (int i = idx; i < n8; i += stride) {
    float4 v0 = s[2 * i], v1 = s[2 * i + 1];
    int lo = 0, hi = 0;
    lo = __builtin_amdgcn_cvt_pk_fp8_f32(v0.x * scale, v0.y * scale, lo, false);
    lo = __builtin_amdgcn_cvt_pk_fp8_f32(v0.z * scale, v0.w * scale, lo, true);
    hi = __builtin_amdgcn_cvt_pk_fp8_f32(v1.x * scale, v1.y * scale, hi, false);
    hi = __builtin_amdgcn_cvt_pk_fp8_f32(v1.z * scale, v1.w * scale, hi, true);
    dst[i] = uint2{(unsigned)lo, (unsigned)hi};
  }
}

__device__ __forceinline__ void gload_lds16(const void* g, void* l) {
  __builtin_amdgcn_global_load_lds(
      (const __attribute__((address_space(1))) void*)g,
      (__attribute__((address_space(3))) void*)l, 16, 0, 0);
}

// ---------------- fused fp8 GEMM + logsumexp + target grab ----------------
// r13 kernel with A taken OUT of LDS: af[m] is loaded directly global->VGPR
// (2x global_load_dwordx4 per frag; A panels are XCD-pinned by the map, so
// these are L2 hits). LDS now stages B only: reads/tile 192->128 b128 (-33%),
// DMA writes 64KB->32KB (-50%) -> LDS pipe drops below the MFMA pipe's 2211
// cyc/tile (r13 measured: LDS ~3100 binding, MfmaUtil 40%).
// Per-tile issue order: A(t) reg-loads FIRST (8 instr), then B(t+1) DMA (4) —
// in-order vmcnt lets the compiler wait A via vmcnt(4) while B flies; the
// end-of-tile vmcnt(0) pays only for B (full tile of flight). ONE barrier/tile.
// 256x256x128 tile, 8 waves (4M x 2N; wave = 64 rows x 128 cols), 2 LDS dbuf
// of 32KB (B only). MFMA: mfma_scale_f32_16x16x128_f8f6f4, unit scales 0x7F.
// LDS layout per buffer: B[256][128B]; chunk (row,j) holds global chunk
// (row, j^(row&7)) — pre-swizzled source, swizzled read (#21).
// C-layout 16x16 (dtype-independent, m89): col = lane&15, row = (lane>>4)*4+reg.
// Block->(split,mblk) map: r9's XCD-affinity grouping (FETCH 388MB proven).
__global__ __launch_bounds__(512, 2) void fused_lse(
    const uint8_t* __restrict__ Wb,  // [V][H] fp8 (pre-scaled by 64)
    const uint8_t* __restrict__ Ab,  // [M][H] fp8
    const float* __restrict__ bias,  // [V]
    const int* __restrict__ target,  // [M]
    float4* __restrict__ partials)   // [NSPLIT][M] : (m, s, tgt_logit, 0)
{
  const int bid = blockIdx.x;
  const int gg = bid >> 8, r = bid & 255;
  int split, mblk;
  if (gg < 15) { int j = r >> 3; split = gg * 8 + (j & 7); mblk = (r & 7) * 4 + (j >> 3); }
  else         { split = 120 + (r >> 5); mblk = r & 31; }   // last group: 5 splits x 32

  const int tid = threadIdx.x;
  const int lane = tid & 63;
  const int w  = tid >> 6;     // 0..7
  const int wm = w >> 1;       // 0..3 : 64-row band
  const int wn = w & 1;        // 0..1 : 128-col half
  const int g  = lane >> 4;    // k-group (reads) / row-group (C layout)
  const int li = lane & 15;
  const int rowbase = mblk * BM;
  const int n0 = split * BN;

  __shared__ __align__(16) uint8_t lds[2][32768];   // per buf: B 32KB (A is reg-direct)

  f32x4 acc[4][8];   // [m][n] : rows wm*64+m*16, cols wn*128+n*16
  const f32x4 vzero = {0.f, 0.f, 0.f, 0.f};
#pragma unroll
  for (int m = 0; m < 4; ++m)
#pragma unroll
    for (int n = 0; n < 8; ++n) acc[m][n] = vzero;

  // B staging geometry (32 segs of 1KB; wave w owns segs 4w..4w+3).
  // chunk c = seg*64+lane; row=c>>3, col=c&7; source col ^= row&7.
  int goff[4], lofs[4];
#pragma unroll
  for (int it = 0; it < 4; ++it) {
    int seg = 4 * w + it, c = seg * 64 + lane;
    int row = c >> 3, col = c & 7;
    goff[it] = row * kH + ((col ^ (row & 7)) << 4);   // fp8: row stride = kH bytes
    lofs[it] = seg * 1024;
  }

  const uint8_t* Agp = Ab + (size_t)rowbase * kH;
  const uint8_t* Bgp = Wb + (size_t)n0 * kH;

  // A: per-lane direct-load base pointers (row = wm*64+m*16+li, k-base g*32)
  const uint8_t* Aptr[4];
#pragma unroll
  for (int m = 0; m < 4; ++m)
    Aptr[m] = Agp + (size_t)(wm * 64 + m * 16 + li) * kH + g * 32;

  // B fragment rows
  int rbN[8];
#pragma unroll
  for (int n = 0; n < 8; ++n) rbN[n] = wn * 128 + n * 16 + li;

  // read one 32B B-frag from LDS: lane's k-bytes [g*32,+32) of row rr
  // (2 chunks 2g,2g+1, each XOR-swizzled) — 16-row span per ds_read_b128.
  auto RD = [&](const uint8_t* base, int rr) -> i32x8 {
    int c0 = g * 2;
    union { i32x4 q[2]; i32x8 o; } u;
    u.q[0] = *(const i32x4*)(base + rr * 128 + ((c0 ^ (rr & 7)) << 4));
    u.q[1] = *(const i32x4*)(base + rr * 128 + (((c0 + 1) ^ (rr & 7)) << 4));
    return u.o;
  };

#define MFMA8(am, bn, cc) \
  __builtin_amdgcn_mfma_scale_f32_16x16x128_f8f6f4((am), (bn), (cc), 0, 0, \
      0, 0x7F7F7F7F, 0, 0x7F7F7F7F)

  // prologue: A(0) loads (compiler waits via reg dep) + stage B(0), drain
  i32x8 af[4];
#pragma unroll
  for (int m = 0; m < 4; ++m) {
    union { i32x4 q[2]; i32x8 o; } u;
    u.q[0] = *(const i32x4*)(Aptr[m]);
    u.q[1] = *(const i32x4*)(Aptr[m] + 16);
    af[m] = u.o;
  }
#pragma unroll
  for (int it = 0; it < 4; ++it) gload_lds16(Bgp + goff[it], lds[0] + lofs[it]);
  asm volatile("s_waitcnt vmcnt(0)" ::: "memory");
  __builtin_amdgcn_s_barrier();

  for (int t = 0; t < KT; ++t) {
    const uint8_t* Bs = lds[t & 1];
    uint8_t* Ld = lds[(t + 1) & 1];
    const int kb0 = t << 7;              // this tile's K byte offset
    const int kb1 = (t + 1) << 7;        // next tile's K byte offset
    const bool pf = (t + 1 < KT);        // workgroup-uniform

    // A(t) direct loads (issued FIRST: oldest in vmcnt queue; t=0 already in af)
    if (t > 0) {
#pragma unroll
      for (int m = 0; m < 4; ++m) {
        union { i32x4 q[2]; i32x8 o; } u;
        u.q[0] = *(const i32x4*)(Aptr[m] + kb0);
        u.q[1] = *(const i32x4*)(Aptr[m] + kb0 + 16);
        af[m] = u.o;
      }
    }
    // B(t+1) staging DMA (newest in queue — survives the compiler's A-waits)
    if (pf) {
#pragma unroll
      for (int it = 0; it < 4; ++it) gload_lds16(Bgp + goff[it] + kb1, Ld + lofs[it]);
    }

    // interleaved B reads + MFMA (no mid barriers; compiler schedules lgkmcnt)
    i32x8 bqa0, bqa1, bqb0, bqb1;
    bqa0 = RD(Bs, rbN[0]); bqa1 = RD(Bs, rbN[1]);
    bqb0 = RD(Bs, rbN[2]); bqb1 = RD(Bs, rbN[3]);
#pragma unroll
    for (int m = 0; m < 4; ++m) {
      acc[m][0] = MFMA8(af[m], bqa0, acc[m][0]);
      acc[m][1] = MFMA8(af[m], bqa1, acc[m][1]);
    }
    bqa0 = RD(Bs, rbN[4]); bqa1 = RD(Bs, rbN[5]);
#pragma unroll
    for (int m = 0; m < 4; ++m) {
      acc[m][2] = MFMA8(af[m], bqb0, acc[m][2]);
      acc[m][3] = MFMA8(af[m], bqb1, acc[m][3]);
    }
    bqb0 = RD(Bs, rbN[6]); bqb1 = RD(Bs, rbN[7]);
#pragma unroll
    for (int m = 0; m < 4; ++m) {
      acc[m][4] = MFMA8(af[m], bqa0, acc[m][4]);
      acc[m][5] = MFMA8(af[m], bqa1, acc[m][5]);
    }
#pragma unroll
    for (int m = 0; m < 4; ++m) {
      acc[m][6] = MFMA8(af[m], bqb0, acc[m][6]);
      acc[m][7] = MFMA8(af[m], bqb1, acc[m][7]);
    }

    if (pf) asm volatile("s_waitcnt vmcnt(0)" ::: "memory");  // B(t+1) landed
    __builtin_amdgcn_s_barrier();   // buf handoff: all waves done reading/staging
  }

  // ---- epilogue: undo W x64 pre-scale, bias, LSE partial + target grab ----
  const float inv64 = 0.015625f;
  float bv[8];
#pragma unroll
  for (int n = 0; n < 8; ++n) bv[n] = bias[n0 + wn * 128 + n * 16 + li];

  float4* mrg = (float4*)lds[0];   // [256 rows][2 wn] — all vmem drained
#pragma unroll
  for (int m = 0; m < 4; ++m)
#pragma unroll
    for (int i = 0; i < 4; ++i) {
      float x[8];
#pragma unroll
      for (int n = 0; n < 8; ++n) x[n] = acc[m][n][i] * inv64 + bv[n];
      float tmax = x[0];
#pragma unroll
      for (int n = 1; n < 8; ++n) tmax = fmaxf(tmax, x[n]);
#pragma unroll
      for (int d = 1; d <= 8; d <<= 1) tmax = fmaxf(tmax, __shfl_xor(tmax, d));
      float tsum = 0.f;
#pragma unroll
      for (int n = 0; n < 8; ++n) tsum += __expf(x[n] - tmax);
#pragma unroll
      for (int d = 1; d <= 8; d <<= 1) tsum += __shfl_xor(tsum, d);
      int lrow = wm * 64 + m * 16 + g * 4 + i;
      int tv = target[rowbase + lrow];
      int c = ((tv == IGNORE_INDEX) ? 0 : tv) - (n0 + wn * 128);  // in [0,128)?
      float rt = 0.f;
#pragma unroll
      for (int n = 0; n < 8; ++n)
        rt += ((c >> 4) == n && (c & 15) == li) ? x[n] : 0.f;
#pragma unroll
      for (int d = 1; d <= 8; d <<= 1) rt += __shfl_xor(rt, d);
      if (li == 0) mrg[lrow * 2 + wn] = float4{tmax, tsum, rt, 0.f};
    }
  __syncthreads();
  if (tid < BM) {
    float4 p0 = mrg[tid * 2 + 0], p1 = mrg[tid * 2 + 1];
    float mm = fmaxf(p0.x, p1.x);
    float ss = p0.y * __expf(p0.x - mm) + p1.y * __expf(p1.x - mm);
    partials[(size_t)split * kM + rowbase + tid] = float4{mm, ss, p0.z + p1.z, 0.f};
  }
#undef MFMA8
}

// ---------------- combine split partials -> per-token logp ----------------
// one wave per row; 64 lanes strided over splits, shfl LSE-merge. grid = kM/4.
__global__ __launch_bounds__(256) void combine_lse(
    const float4* __restrict__ partials, float* __restrict__ per_tok, int nsplit)
{
  int row  = blockIdx.x * 4 + (threadIdx.x >> 6);
  int lane = threadIdx.x & 63;
  float m = -1e30f, s = 0.f, t = 0.f;
  for (int sp = lane; sp < nsplit; sp += 64) {
    float4 p = partials[(size_t)sp * kM + row];
    t += p.z;
    float nm = fmaxf(m, p.x);
    s = s * __expf(m - nm) + p.y * __expf(p.x - nm);
    m = nm;
  }
#pragma unroll
  for (int d = 1; d < 64; d <<= 1) {
    float mo = __shfl_xor(m, d), so = __shfl_xor(s, d), to = __shfl_xor(t, d);
    float nm = fmaxf(m, mo);
    s = s * __expf(m - nm) + so * __expf(mo - nm);
    m = nm; t += to;
  }
  if (lane == 0) per_tok[row] = t - (m + logf(s));
}

// ---------------- final scalar loss ----------------
__global__ __launch_bounds__(1024) void final_loss(
    const float* __restrict__ per_tok, const int* __restrict__ target, float* __restrict__ out)
{
  __shared__ float redv[16], redc[16];
  __shared__ float ssum[8], scnt[8];
  int t = threadIdx.x;
  int wid = t >> 6, lane = t & 63;
  for (int b = 0; b < 8; ++b) {
    int row = b * 1024 + t;
    float mk = (target[row] != IGNORE_INDEX) ? 1.f : 0.f;
    float v = per_tok[row] * mk;
#pragma unroll
    for (int d = 1; d <= 32; d <<= 1) { v += __shfl_xor(v, d); mk += __shfl_xor(mk, d); }
    if (lane == 0) { redv[wid] = v; redc[wid] = mk; }
    __syncthreads();
    if (t == 0) {
      float sv = 0.f, sc = 0.f;
      for (int j = 0; j < 16; ++j) { sv += redv[j]; sc += redc[j]; }
      ssum[b] = sv; scnt[b] = sc;
    }
    __syncthreads();
  }
  if (t == 0) {
    float nsum = 0.f, ncnt = 0.f;
    for (int b = 0; b < 4; ++b) { nsum += ssum[b]; ncnt += scnt[b]; }
    float nll = -nsum / ncnt;
    float pref = 0.f;
    for (int b = 0; b < 4; ++b) {
      float avc = ssum[b] / scnt[b];
      float avr = ssum[b + 4] / scnt[b + 4];
      float d = 0.1f * (avc - avr);                 // BETA = 0.1
      float ls = (d >= 0.f) ? -log1pf(__expf(-d)) : d - log1pf(__expf(d));
      pref += ls;
    }
    pref *= 0.25f;                                  // mean over 4 pairs
    out[0] = 1.0f * nll - pref;                     // ALPHA = 1.0
  }
}

extern "C" void kernel_launch(void* const* d_in, const int* in_sizes, int n_in,
                              void* d_out, int out_size, void* d_ws, size_t ws_size,
                              hipStream_t stream) {
  const float* lin_weight = (const float*)d_in[0];  // [V][H]
  const float* input      = (const float*)d_in[1];  // [B2][T][H]
  const int*   target     = (const int*)d_in[2];    // [B2][T]
  const float* bias       = (const float*)d_in[3];  // [V]
  float* out = (float*)d_out;

  uint8_t* ws = (uint8_t*)d_ws;
  size_t offW = 0;
  size_t offA = offW + (size_t)kV * kH;                // 65,536,000 B (fp8)
  size_t offP = offA + (size_t)kM * kH;                // +16,777,216 B
  size_t offT = offP + (size_t)NSPLIT * kM * 16;       // +16,384,000 B
  size_t need = offT + (size_t)kM * 4;
  if (ws_size < need) return;  // clean failure signal (output stays 0)

  uint8_t* Wb = ws + offW;
  uint8_t* Ab = ws + offA;
  float4* partials = (float4*)(ws + offP);
  float*  per_tok  = (float*)(ws + offT);

  // W pre-scaled by 64 (escape e4m3 denormals; undone by inv64 in epilogue)
  cast_to_fp8<<<2048, 256, 0, stream>>>(lin_weight, (uint2*)Wb, kV * kH / 8, 64.0f);
  cast_to_fp8<<<1024, 256, 0, stream>>>(input, (uint2*)Ab, kM * kH / 8, 1.0f);
  fused_lse<<<NWG, 512, 0, stream>>>(Wb, Ab, bias, target, partials);
  combine_lse<<<kM / 4, 256, 0, stream>>>(partials, per_tok, NSPLIT);
  final_loss<<<1, 1024, 0, stream>>>(per_tok, target, out);
}

// Round 15
// 4773.829 us; speedup vs baseline: 1.0016x; 1.0016x over previous
//
#include <hip/hip_runtime.h>
#include <hip/hip_bf16.h>
#include <stdint.h>

#define IGNORE_INDEX (-100)

constexpr int kB2 = 8, kT = 1024, kH = 2048, kV = 32000;
constexpr int kM = kB2 * kT;           // 8192 token rows
constexpr int BM = 256, BN = 256, BK = 128;   // fp8: 128-B rows
constexpr int NSPLIT = 125;            // vocab splits (1 N-tile each)
constexpr int MBLKS = kM / BM;         // 32 row blocks
constexpr int KT = kH / BK;            // 16 K-tiles
constexpr int NWG = NSPLIT * MBLKS;    // 4000 workgroups

typedef int   i32x4  __attribute__((ext_vector_type(4)));
typedef int   i32x8  __attribute__((ext_vector_type(8)));
typedef float f32x4  __attribute__((ext_vector_type(4)));

// ---------------- cast fp32 -> fp8 e4m3 (OCP), optional pre-scale ----------------
__global__ void cast_to_fp8(const float* __restrict__ src, uint2* __restrict__ dst,
                            int n8, float scale) {
  int idx = blockIdx.x * blockDim.x + threadIdx.x;
  int stride = gridDim.x * blockDim.x;
  const float4* s = (const float4*)src;
  for (int i = idx; i < n8; i += stride) {
    float4 v0 = s[2 * i], v1 = s[2 * i + 1];
    int lo = 0, hi = 0;
    lo = __builtin_amdgcn_cvt_pk_fp8_f32(v0.x * scale, v0.y * scale, lo, false);
    lo = __builtin_amdgcn_cvt_pk_fp8_f32(v0.z * scale, v0.w * scale, lo, true);
    hi = __builtin_amdgcn_cvt_pk_fp8_f32(v1.x * scale, v1.y * scale, hi, false);
    hi = __builtin_amdgcn_cvt_pk_fp8_f32(v1.z * scale, v1.w * scale, hi, true);
    dst[i] = uint2{(unsigned)lo, (unsigned)hi};
  }
}

// ---------------- cast fp32 -> fp8 with FRAGMENT PERMUTE for A ----------------
// A'[rg][t][lane] = 32 fp8 bytes of row rg*16+(lane&15), k-elems t*128+(lane>>4)*32.
// In the GEMM, a wave's A-frag load is then base + t*2048 + lane*32 — 2KB
// contiguous per wave (r14's row-strided per-lane gather was the 7x regression).
__global__ void cast_A_perm(const float* __restrict__ src, uint2* __restrict__ dst) {
  int tid = blockIdx.x * blockDim.x + threadIdx.x;   // one thread per 32-B chunk
  int lane = tid & 63;
  int t    = (tid >> 6) & 15;
  int rg   = tid >> 10;                              // 512 row-groups
  int row  = rg * 16 + (lane & 15);
  int kb   = t * 128 + (lane >> 4) * 32;             // element offset
  const float4* s = (const float4*)(src + (size_t)row * kH + kb);  // 32 floats
  uint2 o[4];
#pragma unroll
  for (int j = 0; j < 4; ++j) {
    float4 v0 = s[2 * j], v1 = s[2 * j + 1];
    int lo = 0, hi = 0;
    lo = __builtin_amdgcn_cvt_pk_fp8_f32(v0.x, v0.y, lo, false);
    lo = __builtin_amdgcn_cvt_pk_fp8_f32(v0.z, v0.w, lo, true);
    hi = __builtin_amdgcn_cvt_pk_fp8_f32(v1.x, v1.y, hi, false);
    hi = __builtin_amdgcn_cvt_pk_fp8_f32(v1.z, v1.w, hi, true);
    o[j] = uint2{(unsigned)lo, (unsigned)hi};
  }
  uint2* d = dst + (size_t)tid * 4;                  // coalesced 32-B write
  d[0] = o[0]; d[1] = o[1]; d[2] = o[2]; d[3] = o[3];
}

__device__ __forceinline__ void gload_lds16(const void* g, void* l) {
  __builtin_amdgcn_global_load_lds(
      (const __attribute__((address_space(1))) void*)g,
      (__attribute__((address_space(3))) void*)l, 16, 0, 0);
}

// ---------------- fused fp8 GEMM + logsumexp + target grab ----------------
// r13 structure (one barrier/tile, interleaved ds_read+MFMA, B double-buffered
// in LDS) with A read DIRECTLY from the permuted A' (coalesced 2KB/wave loads,
// L2-resident). LDS stages B only: 128 ds_read_b128 + 32KB DMA per tile ->
// LDS pipe ~1800 cyc < MFMA 2211 cyc -> MFMA-bound.
// Per-tile issue order: A'(t) loads FIRST, then B(t+1) DMA — in-order vmcnt
// means the compiler's wait for af is vmcnt(4) (B keeps flying); the explicit
// end-of-tile vmcnt(0) pays only for B, which had a full tile of flight.
// 256x256x128 tile, 8 waves (4M x 2N). MFMA: mfma_scale_f32_16x16x128_f8f6f4.
// B LDS layout: [256][128B]; chunk (row,j) holds global chunk (row, j^(row&7))
// — pre-swizzled source, swizzled read (#21).
// C-layout 16x16 (dtype-independent, m89): col = lane&15, row = (lane>>4)*4+reg.
// Block->(split,mblk) map: r9's XCD-affinity grouping (FETCH 388MB proven).
__global__ __launch_bounds__(512, 2) void fused_lse(
    const uint8_t* __restrict__ Wb,  // [V][H] fp8 (pre-scaled by 64)
    const uint8_t* __restrict__ Ap,  // A' permuted fp8 (see cast_A_perm)
    const float* __restrict__ bias,  // [V]
    const int* __restrict__ target,  // [M]
    float4* __restrict__ partials)   // [NSPLIT][M] : (m, s, tgt_logit, 0)
{
  const int bid = blockIdx.x;
  const int gg = bid >> 8, r = bid & 255;
  int split, mblk;
  if (gg < 15) { int j = r >> 3; split = gg * 8 + (j & 7); mblk = (r & 7) * 4 + (j >> 3); }
  else         { split = 120 + (r >> 5); mblk = r & 31; }   // last group: 5 splits x 32

  const int tid = threadIdx.x;
  const int lane = tid & 63;
  const int w  = tid >> 6;     // 0..7
  const int wm = w >> 1;       // 0..3 : 64-row band
  const int wn = w & 1;        // 0..1 : 128-col half
  const int g  = lane >> 4;    // k-group (reads) / row-group (C layout)
  const int li = lane & 15;
  const int rowbase = mblk * BM;
  const int n0 = split * BN;

  __shared__ __align__(16) uint8_t lds[2][32768];   // per buf: B 32KB (A is reg-direct)

  f32x4 acc[4][8];   // [m][n] : rows wm*64+m*16, cols wn*128+n*16
  const f32x4 vzero = {0.f, 0.f, 0.f, 0.f};
#pragma unroll
  for (int m = 0; m < 4; ++m)
#pragma unroll
    for (int n = 0; n < 8; ++n) acc[m][n] = vzero;

  // B staging geometry (32 segs of 1KB; wave w owns segs 4w..4w+3).
  // chunk c = seg*64+lane; row=c>>3, col=c&7; source col ^= row&7.
  int goff[4], lofs[4];
#pragma unroll
  for (int it = 0; it < 4; ++it) {
    int seg = 4 * w + it, c = seg * 64 + lane;
    int row = c >> 3, col = c & 7;
    goff[it] = row * kH + ((col ^ (row & 7)) << 4);   // fp8: row stride = kH bytes
    lofs[it] = seg * 1024;
  }

  const uint8_t* Bgp = Wb + (size_t)n0 * kH;

  // A': per-wave coalesced frag pointers. Row-group of (wm*64+m*16+li) is
  // (rowbase>>4) + wm*4 + m; its 16 K-tiles are 2048 B each; lane offset 32 B.
  const uint8_t* Aptr[4];
#pragma unroll
  for (int m = 0; m < 4; ++m)
    Aptr[m] = Ap + ((size_t)(rowbase >> 4) + wm * 4 + m) * (KT * 2048) + lane * 32;

  // B fragment rows
  int rbN[8];
#pragma unroll
  for (int n = 0; n < 8; ++n) rbN[n] = wn * 128 + n * 16 + li;

  // read one 32B B-frag from LDS: lane's k-bytes [g*32,+32) of row rr
  // (2 chunks 2g,2g+1, each XOR-swizzled) — 16-row span per ds_read_b128.
  auto RD = [&](const uint8_t* base, int rr) -> i32x8 {
    int c0 = g * 2;
    union { i32x4 q[2]; i32x8 o; } u;
    u.q[0] = *(const i32x4*)(base + rr * 128 + ((c0 ^ (rr & 7)) << 4));
    u.q[1] = *(const i32x4*)(base + rr * 128 + (((c0 + 1) ^ (rr & 7)) << 4));
    return u.o;
  };

#define MFMA8(am, bn, cc) \
  __builtin_amdgcn_mfma_scale_f32_16x16x128_f8f6f4((am), (bn), (cc), 0, 0, \
      0, 0x7F7F7F7F, 0, 0x7F7F7F7F)

  // prologue: A'(0) loads + stage B(0), drain
  i32x8 af[4];
#pragma unroll
  for (int m = 0; m < 4; ++m) {
    union { i32x4 q[2]; i32x8 o; } u;
    u.q[0] = *(const i32x4*)(Aptr[m]);
    u.q[1] = *(const i32x4*)(Aptr[m] + 16);
    af[m] = u.o;
  }
#pragma unroll
  for (int it = 0; it < 4; ++it) gload_lds16(Bgp + goff[it], lds[0] + lofs[it]);
  asm volatile("s_waitcnt vmcnt(0)" ::: "memory");
  __builtin_amdgcn_s_barrier();

  for (int t = 0; t < KT; ++t) {
    const uint8_t* Bs = lds[t & 1];
    uint8_t* Ld = lds[(t + 1) & 1];
    const int ka0 = t * 2048;            // this tile's A' byte offset
    const int kb1 = (t + 1) << 7;        // next tile's B K byte offset
    const bool pf = (t + 1 < KT);        // workgroup-uniform

    // A'(t) coalesced loads (issued FIRST: oldest in vmcnt queue; t=0 preloaded)
    if (t > 0) {
#pragma unroll
      for (int m = 0; m < 4; ++m) {
        union { i32x4 q[2]; i32x8 o; } u;
        u.q[0] = *(const i32x4*)(Aptr[m] + ka0);
        u.q[1] = *(const i32x4*)(Aptr[m] + ka0 + 16);
        af[m] = u.o;
      }
    }
    // B(t+1) staging DMA (newest in queue — survives the compiler's A-waits)
    if (pf) {
#pragma unroll
      for (int it = 0; it < 4; ++it) gload_lds16(Bgp + goff[it] + kb1, Ld + lofs[it]);
    }

    // interleaved B reads + MFMA (no mid barriers; compiler schedules lgkmcnt)
    i32x8 bqa0, bqa1, bqb0, bqb1;
    bqa0 = RD(Bs, rbN[0]); bqa1 = RD(Bs, rbN[1]);
    bqb0 = RD(Bs, rbN[2]); bqb1 = RD(Bs, rbN[3]);
#pragma unroll
    for (int m = 0; m < 4; ++m) {
      acc[m][0] = MFMA8(af[m], bqa0, acc[m][0]);
      acc[m][1] = MFMA8(af[m], bqa1, acc[m][1]);
    }
    bqa0 = RD(Bs, rbN[4]); bqa1 = RD(Bs, rbN[5]);
#pragma unroll
    for (int m = 0; m < 4; ++m) {
      acc[m][2] = MFMA8(af[m], bqb0, acc[m][2]);
      acc[m][3] = MFMA8(af[m], bqb1, acc[m][3]);
    }
    bqb0 = RD(Bs, rbN[6]); bqb1 = RD(Bs, rbN[7]);
#pragma unroll
    for (int m = 0; m < 4; ++m) {
      acc[m][4] = MFMA8(af[m], bqa0, acc[m][4]);
      acc[m][5] = MFMA8(af[m], bqa1, acc[m][5]);
    }
#pragma unroll
    for (int m = 0; m < 4; ++m) {
      acc[m][6] = MFMA8(af[m], bqb0, acc[m][6]);
      acc[m][7] = MFMA8(af[m], bqb1, acc[m][7]);
    }

    if (pf) asm volatile("s_waitcnt vmcnt(0)" ::: "memory");  // B(t+1) landed
    __builtin_amdgcn_s_barrier();   // buf handoff: all waves done reading/staging
  }

  // ---- epilogue: undo W x64 pre-scale, bias, LSE partial + target grab ----
  const float inv64 = 0.015625f;
  float bv[8];
#pragma unroll
  for (int n = 0; n < 8; ++n) bv[n] = bias[n0 + wn * 128 + n * 16 + li];

  float4* mrg = (float4*)lds[0];   // [256 rows][2 wn] — all vmem drained
#pragma unroll
  for (int m = 0; m < 4; ++m)
#pragma unroll
    for (int i = 0; i < 4; ++i) {
      float x[8];
#pragma unroll
      for (int n = 0; n < 8; ++n) x[n] = acc[m][n][i] * inv64 + bv[n];
      float tmax = x[0];
#pragma unroll
      for (int n = 1; n < 8; ++n) tmax = fmaxf(tmax, x[n]);
#pragma unroll
      for (int d = 1; d <= 8; d <<= 1) tmax = fmaxf(tmax, __shfl_xor(tmax, d));
      float tsum = 0.f;
#pragma unroll
      for (int n = 0; n < 8; ++n) tsum += __expf(x[n] - tmax);
#pragma unroll
      for (int d = 1; d <= 8; d <<= 1) tsum += __shfl_xor(tsum, d);
      int lrow = wm * 64 + m * 16 + g * 4 + i;
      int tv = target[rowbase + lrow];
      int c = ((tv == IGNORE_INDEX) ? 0 : tv) - (n0 + wn * 128);  // in [0,128)?
      float rt = 0.f;
#pragma unroll
      for (int n = 0; n < 8; ++n)
        rt += ((c >> 4) == n && (c & 15) == li) ? x[n] : 0.f;
#pragma unroll
      for (int d = 1; d <= 8; d <<= 1) rt += __shfl_xor(rt, d);
      if (li == 0) mrg[lrow * 2 + wn] = float4{tmax, tsum, rt, 0.f};
    }
  __syncthreads();
  if (tid < BM) {
    float4 p0 = mrg[tid * 2 + 0], p1 = mrg[tid * 2 + 1];
    float mm = fmaxf(p0.x, p1.x);
    float ss = p0.y * __expf(p0.x - mm) + p1.y * __expf(p1.x - mm);
    partials[(size_t)split * kM + rowbase + tid] = float4{mm, ss, p0.z + p1.z, 0.f};
  }
#undef MFMA8
}

// ---------------- combine split partials -> per-token logp ----------------
// one wave per row; 64 lanes strided over splits, shfl LSE-merge. grid = kM/4.
__global__ __launch_bounds__(256) void combine_lse(
    const float4* __restrict__ partials, float* __restrict__ per_tok, int nsplit)
{
  int row  = blockIdx.x * 4 + (threadIdx.x >> 6);
  int lane = threadIdx.x & 63;
  float m = -1e30f, s = 0.f, t = 0.f;
  for (int sp = lane; sp < nsplit; sp += 64) {
    float4 p = partials[(size_t)sp * kM + row];
    t += p.z;
    float nm = fmaxf(m, p.x);
    s = s * __expf(m - nm) + p.y * __expf(p.x - nm);
    m = nm;
  }
#pragma unroll
  for (int d = 1; d < 64; d <<= 1) {
    float mo = __shfl_xor(m, d), so = __shfl_xor(s, d), to = __shfl_xor(t, d);
    float nm = fmaxf(m, mo);
    s = s * __expf(m - nm) + so * __expf(mo - nm);
    m = nm; t += to;
  }
  if (lane == 0) per_tok[row] = t - (m + logf(s));
}

// ---------------- final scalar loss ----------------
__global__ __launch_bounds__(1024) void final_loss(
    const float* __restrict__ per_tok, const int* __restrict__ target, float* __restrict__ out)
{
  __shared__ float redv[16], redc[16];
  __shared__ float ssum[8], scnt[8];
  int t = threadIdx.x;
  int wid = t >> 6, lane = t & 63;
  for (int b = 0; b < 8; ++b) {
    int row = b * 1024 + t;
    float mk = (target[row] != IGNORE_INDEX) ? 1.f : 0.f;
    float v = per_tok[row] * mk;
#pragma unroll
    for (int d = 1; d <= 32; d <<= 1) { v += __shfl_xor(v, d); mk += __shfl_xor(mk, d); }
    if (lane == 0) { redv[wid] = v; redc[wid] = mk; }
    __syncthreads();
    if (t == 0) {
      float sv = 0.f, sc = 0.f;
      for (int j = 0; j < 16; ++j) { sv += redv[j]; sc += redc[j]; }
      ssum[b] = sv; scnt[b] = sc;
    }
    __syncthreads();
  }
  if (t == 0) {
    float nsum = 0.f, ncnt = 0.f;
    for (int b = 0; b < 4; ++b) { nsum += ssum[b]; ncnt += scnt[b]; }
    float nll = -nsum / ncnt;
    float pref = 0.f;
    for (int b = 0; b < 4; ++b) {
      float avc = ssum[b] / scnt[b];
      float avr = ssum[b + 4] / scnt[b + 4];
      float d = 0.1f * (avc - avr);                 // BETA = 0.1
      float ls = (d >= 0.f) ? -log1pf(__expf(-d)) : d - log1pf(__expf(d));
      pref += ls;
    }
    pref *= 0.25f;                                  // mean over 4 pairs
    out[0] = 1.0f * nll - pref;                     // ALPHA = 1.0
  }
}

extern "C" void kernel_launch(void* const* d_in, const int* in_sizes, int n_in,
                              void* d_out, int out_size, void* d_ws, size_t ws_size,
                              hipStream_t stream) {
  const float* lin_weight = (const float*)d_in[0];  // [V][H]
  const float* input      = (const float*)d_in[1];  // [B2][T][H]
  const int*   target     = (const int*)d_in[2];    // [B2][T]
  const float* bias       = (const float*)d_in[3];  // [V]
  float* out = (float*)d_out;

  uint8_t* ws = (uint8_t*)d_ws;
  size_t offW = 0;
  size_t offA = offW + (size_t)kV * kH;                // 65,536,000 B (fp8)
  size_t offP = offA + (size_t)kM * kH;                // +16,777,216 B (A' permuted)
  size_t offT = offP + (size_t)NSPLIT * kM * 16;       // +16,384,000 B
  size_t need = offT + (size_t)kM * 4;
  if (ws_size < need) return;  // clean failure signal (output stays 0)

  uint8_t* Wb = ws + offW;
  uint8_t* Ap = ws + offA;
  float4* partials = (float4*)(ws + offP);
  float*  per_tok  = (float*)(ws + offT);

  // W pre-scaled by 64 (escape e4m3 denormals; undone by inv64 in epilogue)
  cast_to_fp8<<<2048, 256, 0, stream>>>(lin_weight, (uint2*)Wb, kV * kH / 8, 64.0f);
  cast_A_perm<<<kM * kH / 32 / 256, 256, 0, stream>>>(input, (uint2*)Ap);
  fused_lse<<<NWG, 512, 0, stream>>>(Wb, Ap, bias, target, partials);
  combine_lse<<<kM / 4, 256, 0, stream>>>(partials, per_tok, NSPLIT);
  final_loss<<<1, 1024, 0, stream>>>(per_tok, target, out);
}

// Round 16
// 4734.604 us; speedup vs baseline: 1.0099x; 1.0083x over previous
//
#include <hip/hip_runtime.h>
#include <hip/hip_bf16.h>
#include <stdint.h>

#define IGNORE_INDEX (-100)

constexpr int kB2 = 8, kT = 1024, kH = 2048, kV = 32000;
constexpr int kM = kB2 * kT;           // 8192 token rows
constexpr int BM = 256, BN = 256, BK = 128;   // fp8: 128-B rows
constexpr int NSPLIT = 125;            // vocab splits (1 N-tile each)
constexpr int MBLKS = kM / BM;         // 32 row blocks
constexpr int KT = kH / BK;            // 16 K-tiles
constexpr int NWG = NSPLIT * MBLKS;    // 4000 workgroups

typedef int   i32x4  __attribute__((ext_vector_type(4)));
typedef int   i32x8  __attribute__((ext_vector_type(8)));
typedef float f32x4  __attribute__((ext_vector_type(4)));

// ---------------- cast fp32 -> fp8 e4m3 (OCP), optional pre-scale ----------------
__global__ void cast_to_fp8(const float* __restrict__ src, uint2* __restrict__ dst,
                            int n8, float scale) {
  int idx = blockIdx.x * blockDim.x + threadIdx.x;
  int stride = gridDim.x * blockDim.x;
  const float4* s = (const float4*)src;
  for (int i = idx; i < n8; i += stride) {
    float4 v0 = s[2 * i], v1 = s[2 * i + 1];
    int lo = 0, hi = 0;
    lo = __builtin_amdgcn_cvt_pk_fp8_f32(v0.x * scale, v0.y * scale, lo, false);
    lo = __builtin_amdgcn_cvt_pk_fp8_f32(v0.z * scale, v0.w * scale, lo, true);
    hi = __builtin_amdgcn_cvt_pk_fp8_f32(v1.x * scale, v1.y * scale, hi, false);
    hi = __builtin_amdgcn_cvt_pk_fp8_f32(v1.z * scale, v1.w * scale, hi, true);
    dst[i] = uint2{(unsigned)lo, (unsigned)hi};
  }
}

// ---------------- cast fp32 -> fp8 with FRAGMENT PERMUTE for A ----------------
// A'[rg][t][lane] = 32 fp8 bytes of row rg*16+(lane&15), k-elems t*128+(lane>>4)*32.
// In the GEMM, a wave's A-frag load is then base + t*2048 + lane*32 — 2KB
// contiguous per wave.
__global__ void cast_A_perm(const float* __restrict__ src, uint2* __restrict__ dst) {
  int tid = blockIdx.x * blockDim.x + threadIdx.x;   // one thread per 32-B chunk
  int lane = tid & 63;
  int t    = (tid >> 6) & 15;
  int rg   = tid >> 10;                              // 512 row-groups
  int row  = rg * 16 + (lane & 15);
  int kb   = t * 128 + (lane >> 4) * 32;             // element offset
  const float4* s = (const float4*)(src + (size_t)row * kH + kb);  // 32 floats
  uint2 o[4];
#pragma unroll
  for (int j = 0; j < 4; ++j) {
    float4 v0 = s[2 * j], v1 = s[2 * j + 1];
    int lo = 0, hi = 0;
    lo = __builtin_amdgcn_cvt_pk_fp8_f32(v0.x, v0.y, lo, false);
    lo = __builtin_amdgcn_cvt_pk_fp8_f32(v0.z, v0.w, lo, true);
    hi = __builtin_amdgcn_cvt_pk_fp8_f32(v1.x, v1.y, hi, false);
    hi = __builtin_amdgcn_cvt_pk_fp8_f32(v1.z, v1.w, hi, true);
    o[j] = uint2{(unsigned)lo, (unsigned)hi};
  }
  uint2* d = dst + (size_t)tid * 4;                  // coalesced 32-B write
  d[0] = o[0]; d[1] = o[1]; d[2] = o[2]; d[3] = o[3];
}

__device__ __forceinline__ void gload_lds16(const void* g, void* l) {
  __builtin_amdgcn_global_load_lds(
      (const __attribute__((address_space(1))) void*)g,
      (__attribute__((address_space(3))) void*)l, 16, 0, 0);
}

// ---------------- fused fp8 GEMM + logsumexp + target grab ----------------
// r15 kernel + LDS PADDED TO 96KB to force 1 BLOCK/CU. Evidence (r10/r11/r14/
// r15 vs r9/r12/r13): every 2-blocks/CU variant — regardless of map or A-load
// pattern — shows the same ~6.5GB symmetric fetch+write fabric thrash
// (concurrent per-XCD working set ~12MB >> 4MB L2); every 1-block/CU variant
// is clean (FETCH 388MB). The pad restores r13's concurrency while keeping
// A out of LDS (LDS pipe 128 b128 + 32KB DMA per tile < MFMA 2211 cyc).
// A is read directly from permuted A' (coalesced 2KB/wave, L2-resident).
// Per-tile issue order: A'(t) loads FIRST, then B(t+1) DMA — in-order vmcnt
// means the compiler's wait for af leaves the B DMA flying; the end-of-tile
// vmcnt(0) pays only for B (full tile of flight). ONE barrier/tile.
// 256x256x128 tile, 8 waves (4M x 2N). MFMA: mfma_scale_f32_16x16x128_f8f6f4.
// B LDS layout: [256][128B]; chunk (row,j) holds global chunk (row, j^(row&7))
// — pre-swizzled source, swizzled read (#21).
// C-layout 16x16 (dtype-independent, m89): col = lane&15, row = (lane>>4)*4+reg.
// Block->(split,mblk) map: r9's XCD-affinity grouping (FETCH 388MB proven).
__global__ __launch_bounds__(512, 2) void fused_lse(
    const uint8_t* __restrict__ Wb,  // [V][H] fp8 (pre-scaled by 64)
    const uint8_t* __restrict__ Ap,  // A' permuted fp8 (see cast_A_perm)
    const float* __restrict__ bias,  // [V]
    const int* __restrict__ target,  // [M]
    float4* __restrict__ partials)   // [NSPLIT][M] : (m, s, tgt_logit, 0)
{
  const int bid = blockIdx.x;
  const int gg = bid >> 8, r = bid & 255;
  int split, mblk;
  if (gg < 15) { int j = r >> 3; split = gg * 8 + (j & 7); mblk = (r & 7) * 4 + (j >> 3); }
  else         { split = 120 + (r >> 5); mblk = r & 31; }   // last group: 5 splits x 32

  const int tid = threadIdx.x;
  const int lane = tid & 63;
  const int w  = tid >> 6;     // 0..7
  const int wm = w >> 1;       // 0..3 : 64-row band
  const int wn = w & 1;        // 0..1 : 128-col half
  const int g  = lane >> 4;    // k-group (reads) / row-group (C layout)
  const int li = lane & 15;
  const int rowbase = mblk * BM;
  const int n0 = split * BN;

  // [0],[1]: B double-buffer. [2]: residency pad — 96KB > 80KB forces
  // 1 block/CU (2 co-resident blocks thrash L2; see header comment).
  __shared__ __align__(16) uint8_t lds[3][32768];

  f32x4 acc[4][8];   // [m][n] : rows wm*64+m*16, cols wn*128+n*16
  const f32x4 vzero = {0.f, 0.f, 0.f, 0.f};
#pragma unroll
  for (int m = 0; m < 4; ++m)
#pragma unroll
    for (int n = 0; n < 8; ++n) acc[m][n] = vzero;

  // B staging geometry (32 segs of 1KB; wave w owns segs 4w..4w+3).
  // chunk c = seg*64+lane; row=c>>3, col=c&7; source col ^= row&7.
  int goff[4], lofs[4];
#pragma unroll
  for (int it = 0; it < 4; ++it) {
    int seg = 4 * w + it, c = seg * 64 + lane;
    int row = c >> 3, col = c & 7;
    goff[it] = row * kH + ((col ^ (row & 7)) << 4);   // fp8: row stride = kH bytes
    lofs[it] = seg * 1024;
  }

  const uint8_t* Bgp = Wb + (size_t)n0 * kH;

  // A': per-wave coalesced frag pointers. Row-group of (wm*64+m*16+li) is
  // (rowbase>>4) + wm*4 + m; its 16 K-tiles are 2048 B each; lane offset 32 B.
  const uint8_t* Aptr[4];
#pragma unroll
  for (int m = 0; m < 4; ++m)
    Aptr[m] = Ap + ((size_t)(rowbase >> 4) + wm * 4 + m) * (KT * 2048) + lane * 32;

  // B fragment rows
  int rbN[8];
#pragma unroll
  for (int n = 0; n < 8; ++n) rbN[n] = wn * 128 + n * 16 + li;

  // read one 32B B-frag from LDS: lane's k-bytes [g*32,+32) of row rr
  // (2 chunks 2g,2g+1, each XOR-swizzled) — 16-row span per ds_read_b128.
  auto RD = [&](const uint8_t* base, int rr) -> i32x8 {
    int c0 = g * 2;
    union { i32x4 q[2]; i32x8 o; } u;
    u.q[0] = *(const i32x4*)(base + rr * 128 + ((c0 ^ (rr & 7)) << 4));
    u.q[1] = *(const i32x4*)(base + rr * 128 + (((c0 + 1) ^ (rr & 7)) << 4));
    return u.o;
  };

#define MFMA8(am, bn, cc) \
  __builtin_amdgcn_mfma_scale_f32_16x16x128_f8f6f4((am), (bn), (cc), 0, 0, \
      0, 0x7F7F7F7F, 0, 0x7F7F7F7F)

  // prologue: A'(0) loads + stage B(0), drain
  i32x8 af[4];
#pragma unroll
  for (int m = 0; m < 4; ++m) {
    union { i32x4 q[2]; i32x8 o; } u;
    u.q[0] = *(const i32x4*)(Aptr[m]);
    u.q[1] = *(const i32x4*)(Aptr[m] + 16);
    af[m] = u.o;
  }
#pragma unroll
  for (int it = 0; it < 4; ++it) gload_lds16(Bgp + goff[it], lds[0] + lofs[it]);
  asm volatile("s_waitcnt vmcnt(0)" ::: "memory");
  __builtin_amdgcn_s_barrier();

  for (int t = 0; t < KT; ++t) {
    const uint8_t* Bs = lds[t & 1];
    uint8_t* Ld = lds[(t + 1) & 1];
    const int ka0 = t * 2048;            // this tile's A' byte offset
    const int kb1 = (t + 1) << 7;        // next tile's B K byte offset
    const bool pf = (t + 1 < KT);        // workgroup-uniform

    // A'(t) coalesced loads (issued FIRST: oldest in vmcnt queue; t=0 preloaded)
    if (t > 0) {
#pragma unroll
      for (int m = 0; m < 4; ++m) {
        union { i32x4 q[2]; i32x8 o; } u;
        u.q[0] = *(const i32x4*)(Aptr[m] + ka0);
        u.q[1] = *(const i32x4*)(Aptr[m] + ka0 + 16);
        af[m] = u.o;
      }
    }
    // B(t+1) staging DMA (newest in queue — survives the compiler's A-waits)
    if (pf) {
#pragma unroll
      for (int it = 0; it < 4; ++it) gload_lds16(Bgp + goff[it] + kb1, Ld + lofs[it]);
    }

    // interleaved B reads + MFMA (no mid barriers; compiler schedules lgkmcnt)
    i32x8 bqa0, bqa1, bqb0, bqb1;
    bqa0 = RD(Bs, rbN[0]); bqa1 = RD(Bs, rbN[1]);
    bqb0 = RD(Bs, rbN[2]); bqb1 = RD(Bs, rbN[3]);
#pragma unroll
    for (int m = 0; m < 4; ++m) {
      acc[m][0] = MFMA8(af[m], bqa0, acc[m][0]);
      acc[m][1] = MFMA8(af[m], bqa1, acc[m][1]);
    }
    bqa0 = RD(Bs, rbN[4]); bqa1 = RD(Bs, rbN[5]);
#pragma unroll
    for (int m = 0; m < 4; ++m) {
      acc[m][2] = MFMA8(af[m], bqb0, acc[m][2]);
      acc[m][3] = MFMA8(af[m], bqb1, acc[m][3]);
    }
    bqb0 = RD(Bs, rbN[6]); bqb1 = RD(Bs, rbN[7]);
#pragma unroll
    for (int m = 0; m < 4; ++m) {
      acc[m][4] = MFMA8(af[m], bqa0, acc[m][4]);
      acc[m][5] = MFMA8(af[m], bqa1, acc[m][5]);
    }
#pragma unroll
    for (int m = 0; m < 4; ++m) {
      acc[m][6] = MFMA8(af[m], bqb0, acc[m][6]);
      acc[m][7] = MFMA8(af[m], bqb1, acc[m][7]);
    }

    if (pf) asm volatile("s_waitcnt vmcnt(0)" ::: "memory");  // B(t+1) landed
    __builtin_amdgcn_s_barrier();   // buf handoff: all waves done reading/staging
  }

  // ---- epilogue: undo W x64 pre-scale, bias, LSE partial + target grab ----
  const float inv64 = 0.015625f;
  float bv[8];
#pragma unroll
  for (int n = 0; n < 8; ++n) bv[n] = bias[n0 + wn * 128 + n * 16 + li];

  float4* mrg = (float4*)lds[0];   // [256 rows][2 wn] — all vmem drained
#pragma unroll
  for (int m = 0; m < 4; ++m)
#pragma unroll
    for (int i = 0; i < 4; ++i) {
      float x[8];
#pragma unroll
      for (int n = 0; n < 8; ++n) x[n] = acc[m][n][i] * inv64 + bv[n];
      float tmax = x[0];
#pragma unroll
      for (int n = 1; n < 8; ++n) tmax = fmaxf(tmax, x[n]);
#pragma unroll
      for (int d = 1; d <= 8; d <<= 1) tmax = fmaxf(tmax, __shfl_xor(tmax, d));
      float tsum = 0.f;
#pragma unroll
      for (int n = 0; n < 8; ++n) tsum += __expf(x[n] - tmax);
#pragma unroll
      for (int d = 1; d <= 8; d <<= 1) tsum += __shfl_xor(tsum, d);
      int lrow = wm * 64 + m * 16 + g * 4 + i;
      int tv = target[rowbase + lrow];
      int c = ((tv == IGNORE_INDEX) ? 0 : tv) - (n0 + wn * 128);  // in [0,128)?
      float rt = 0.f;
#pragma unroll
      for (int n = 0; n < 8; ++n)
        rt += ((c >> 4) == n && (c & 15) == li) ? x[n] : 0.f;
#pragma unroll
      for (int d = 1; d <= 8; d <<= 1) rt += __shfl_xor(rt, d);
      if (li == 0) mrg[lrow * 2 + wn] = float4{tmax, tsum, rt, 0.f};
    }
  __syncthreads();
  if (tid < BM) {
    float4 p0 = mrg[tid * 2 + 0], p1 = mrg[tid * 2 + 1];
    float mm = fmaxf(p0.x, p1.x);
    float ss = p0.y * __expf(p0.x - mm) + p1.y * __expf(p1.x - mm);
    partials[(size_t)split * kM + rowbase + tid] = float4{mm, ss, p0.z + p1.z, 0.f};
  }
#undef MFMA8
}

// ---------------- combine split partials -> per-token logp ----------------
// one wave per row; 64 lanes strided over splits, shfl LSE-merge. grid = kM/4.
__global__ __launch_bounds__(256) void combine_lse(
    const float4* __restrict__ partials, float* __restrict__ per_tok, int nsplit)
{
  int row  = blockIdx.x * 4 + (threadIdx.x >> 6);
  int lane = threadIdx.x & 63;
  float m = -1e30f, s = 0.f, t = 0.f;
  for (int sp = lane; sp < nsplit; sp += 64) {
    float4 p = partials[(size_t)sp * kM + row];
    t += p.z;
    float nm = fmaxf(m, p.x);
    s = s * __expf(m - nm) + p.y * __expf(p.x - nm);
    m = nm;
  }
#pragma unroll
  for (int d = 1; d < 64; d <<= 1) {
    float mo = __shfl_xor(m, d), so = __shfl_xor(s, d), to = __shfl_xor(t, d);
    float nm = fmaxf(m, mo);
    s = s * __expf(m - nm) + so * __expf(mo - nm);
    m = nm; t += to;
  }
  if (lane == 0) per_tok[row] = t - (m + logf(s));
}

// ---------------- final scalar loss ----------------
__global__ __launch_bounds__(1024) void final_loss(
    const float* __restrict__ per_tok, const int* __restrict__ target, float* __restrict__ out)
{
  __shared__ float redv[16], redc[16];
  __shared__ float ssum[8], scnt[8];
  int t = threadIdx.x;
  int wid = t >> 6, lane = t & 63;
  for (int b = 0; b < 8; ++b) {
    int row = b * 1024 + t;
    float mk = (target[row] != IGNORE_INDEX) ? 1.f : 0.f;
    float v = per_tok[row] * mk;
#pragma unroll
    for (int d = 1; d <= 32; d <<= 1) { v += __shfl_xor(v, d); mk += __shfl_xor(mk, d); }
    if (lane == 0) { redv[wid] = v; redc[wid] = mk; }
    __syncthreads();
    if (t == 0) {
      float sv = 0.f, sc = 0.f;
      for (int j = 0; j < 16; ++j) { sv += redv[j]; sc += redc[j]; }
      ssum[b] = sv; scnt[b] = sc;
    }
    __syncthreads();
  }
  if (t == 0) {
    float nsum = 0.f, ncnt = 0.f;
    for (int b = 0; b < 4; ++b) { nsum += ssum[b]; ncnt += scnt[b]; }
    float nll = -nsum / ncnt;
    float pref = 0.f;
    for (int b = 0; b < 4; ++b) {
      float avc = ssum[b] / scnt[b];
      float avr = ssum[b + 4] / scnt[b + 4];
      float d = 0.1f * (avc - avr);                 // BETA = 0.1
      float ls = (d >= 0.f) ? -log1pf(__expf(-d)) : d - log1pf(__expf(d));
      pref += ls;
    }
    pref *= 0.25f;                                  // mean over 4 pairs
    out[0] = 1.0f * nll - pref;                     // ALPHA = 1.0
  }
}

extern "C" void kernel_launch(void* const* d_in, const int* in_sizes, int n_in,
                              void* d_out, int out_size, void* d_ws, size_t ws_size,
                              hipStream_t stream) {
  const float* lin_weight = (const float*)d_in[0];  // [V][H]
  const float* input      = (const float*)d_in[1];  // [B2][T][H]
  const int*   target     = (const int*)d_in[2];    // [B2][T]
  const float* bias       = (const float*)d_in[3];  // [V]
  float* out = (float*)d_out;

  uint8_t* ws = (uint8_t*)d_ws;
  size_t offW = 0;
  size_t offA = offW + (size_t)kV * kH;                // 65,536,000 B (fp8)
  size_t offP = offA + (size_t)kM * kH;                // +16,777,216 B (A' permuted)
  size_t offT = offP + (size_t)NSPLIT * kM * 16;       // +16,384,000 B
  size_t need = offT + (size_t)kM * 4;
  if (ws_size < need) return;  // clean failure signal (output stays 0)

  uint8_t* Wb = ws + offW;
  uint8_t* Ap = ws + offA;
  float4* partials = (float4*)(ws + offP);
  float*  per_tok  = (float*)(ws + offT);

  // W pre-scaled by 64 (escape e4m3 denormals; undone by inv64 in epilogue)
  cast_to_fp8<<<2048, 256, 0, stream>>>(lin_weight, (uint2*)Wb, kV * kH / 8, 64.0f);
  cast_A_perm<<<kM * kH / 32 / 256, 256, 0, stream>>>(input, (uint2*)Ap);
  fused_lse<<<NWG, 512, 0, stream>>>(Wb, Ap, bias, target, partials);
  combine_lse<<<kM / 4, 256, 0, stream>>>(partials, per_tok, NSPLIT);
  final_loss<<<1, 1024, 0, stream>>>(per_tok, target, out);
}

// Round 17
// 631.961 us; speedup vs baseline: 7.5659x; 7.4919x over previous
//
#include <hip/hip_runtime.h>
#include <hip/hip_bf16.h>
#include <stdint.h>

#define IGNORE_INDEX (-100)

constexpr int kB2 = 8, kT = 1024, kH = 2048, kV = 32000;
constexpr int kM = kB2 * kT;           // 8192 token rows
constexpr int BM = 256, BN = 256, BK = 128;   // fp8: 128-B rows
constexpr int NSPLIT = 125;            // vocab splits (1 N-tile each)
constexpr int MBLKS = kM / BM;         // 32 row blocks
constexpr int KT = kH / BK;            // 16 K-tiles
constexpr int NWG = NSPLIT * MBLKS;    // 4000 workgroups

typedef int   i32x4  __attribute__((ext_vector_type(4)));
typedef int   i32x8  __attribute__((ext_vector_type(8)));
typedef float f32x4  __attribute__((ext_vector_type(4)));

// ---------------- cast fp32 -> fp8 e4m3 (OCP), optional pre-scale ----------------
__global__ void cast_to_fp8(const float* __restrict__ src, uint2* __restrict__ dst,
                            int n8, float scale) {
  int idx = blockIdx.x * blockDim.x + threadIdx.x;
  int stride = gridDim.x * blockDim.x;
  const float4* s = (const float4*)src;
  for (int i = idx; i < n8; i += stride) {
    float4 v0 = s[2 * i], v1 = s[2 * i + 1];
    int lo = 0, hi = 0;
    lo = __builtin_amdgcn_cvt_pk_fp8_f32(v0.x * scale, v0.y * scale, lo, false);
    lo = __builtin_amdgcn_cvt_pk_fp8_f32(v0.z * scale, v0.w * scale, lo, true);
    hi = __builtin_amdgcn_cvt_pk_fp8_f32(v1.x * scale, v1.y * scale, hi, false);
    hi = __builtin_amdgcn_cvt_pk_fp8_f32(v1.z * scale, v1.w * scale, hi, true);
    dst[i] = uint2{(unsigned)lo, (unsigned)hi};
  }
}

__device__ __forceinline__ void gload_lds16(const void* g, void* l) {
  __builtin_amdgcn_global_load_lds(
      (const __attribute__((address_space(1))) void*)g,
      (__attribute__((address_space(3))) void*)l, 16, 0, 0);
}

// ---------------- fused fp8 GEMM + logsumexp + target grab ----------------
// ROUND-13 KERNEL, REVERTED VERBATIM (best passing config: 631us total,
// fused ~595us, MfmaUtil 40%, FETCH 388MB, WRITE 16MB).
// Post-r16 lesson recorded: replacing A's global_load_lds staging with
// per-lane vector loads (r14 strided, r15 coalesced-A', r16 1-block/CU)
// ALWAYS triggers a ~6.5GB symmetric fetch+write L2/fabric-thrash mode
// (MfmaUtil 4.6%, 7x regression) — independent of coalescing and occupancy.
// All global->LDS traffic in this family must go through global_load_lds.
// Structure: ONE phase / ONE barrier per K-tile:
//   STAGE(t+1 -> buf^1); interleaved {ds_read, MFMA}; vmcnt(0); barrier.
// Mid-tile barriers are correctness-unnecessary (stage writes buf^1, reads
// target buf; the end-of-tile barrier closes the reuse hazard because each
// wave's reads are consumed by its MFMAs before it can reach the barrier).
// The compiler interleaves ds_read with MFMA (lgkmcnt scheduling) and the
// 2 waves/SIMD slip within the tile — LDS pipe (~2800 cyc/tile) and MFMA
// pipe (~2211 cyc/tile) overlap instead of serializing.
// 256x256x128 tile, 8 waves (4M x 2N; wave = 64 rows x 128 cols), 2 LDS dbuf.
// MFMA: mfma_scale_f32_16x16x128_f8f6f4 (fp8 x fp8, unit e8m0 scales 0x7F).
// B-frags read in ping-pong pairs (bqa/bqb) to bound operand liveness.
// LDS layout per buffer: A[256][128B] | B[256][128B]; chunk (row,j) holds
// global chunk (row, j^(row&7)) — pre-swizzled source, swizzled read (#21).
// C-layout 16x16 (dtype-independent, m89): col = lane&15, row = (lane>>4)*4+reg.
// Block->(split,mblk) map: r9's XCD-affinity grouping (FETCH 388MB proven).
__global__ __launch_bounds__(512, 2) void fused_lse(
    const uint8_t* __restrict__ Wb,  // [V][H] fp8 (pre-scaled by 64)
    const uint8_t* __restrict__ Ab,  // [M][H] fp8
    const float* __restrict__ bias,  // [V]
    const int* __restrict__ target,  // [M]
    float4* __restrict__ partials)   // [NSPLIT][M] : (m, s, tgt_logit, 0)
{
  const int bid = blockIdx.x;
  const int gg = bid >> 8, r = bid & 255;
  int split, mblk;
  if (gg < 15) { int j = r >> 3; split = gg * 8 + (j & 7); mblk = (r & 7) * 4 + (j >> 3); }
  else         { split = 120 + (r >> 5); mblk = r & 31; }   // last group: 5 splits x 32

  const int tid = threadIdx.x;
  const int lane = tid & 63;
  const int w  = tid >> 6;     // 0..7
  const int wm = w >> 1;       // 0..3 : 64-row band
  const int wn = w & 1;        // 0..1 : 128-col half
  const int g  = lane >> 4;    // k-group (reads) / row-group (C layout)
  const int li = lane & 15;
  const int rowbase = mblk * BM;
  const int n0 = split * BN;

  __shared__ __align__(16) uint8_t lds[2][65536];   // per buf: A 32KB | B 32KB

  f32x4 acc[4][8];   // [m][n] : rows wm*64+m*16, cols wn*128+n*16
  const f32x4 vzero = {0.f, 0.f, 0.f, 0.f};
#pragma unroll
  for (int m = 0; m < 4; ++m)
#pragma unroll
    for (int n = 0; n < 8; ++n) acc[m][n] = vzero;

  // staging geometry (A and B tiles: 32 segs of 1KB each; wave w owns segs
  // 4w..4w+3). chunk c = seg*64+lane; row=c>>3, col=c&7; source col ^= row&7.
  int goff[4], lofs[4];
#pragma unroll
  for (int it = 0; it < 4; ++it) {
    int seg = 4 * w + it, c = seg * 64 + lane;
    int row = c >> 3, col = c & 7;
    goff[it] = row * kH + ((col ^ (row & 7)) << 4);   // fp8: row stride = kH bytes
    lofs[it] = seg * 1024;
  }

  const uint8_t* Agp = Ab + (size_t)rowbase * kH;
  const uint8_t* Bgp = Wb + (size_t)n0 * kH;

  // fragment rows
  int raM[4], rbN[8];
#pragma unroll
  for (int m = 0; m < 4; ++m) raM[m] = wm * 64 + m * 16 + li;
#pragma unroll
  for (int n = 0; n < 8; ++n) rbN[n] = wn * 128 + n * 16 + li;

  // read one 32B operand frag: lane's k-bytes [g*32, g*32+32) of row rr
  // (2 chunks 2g,2g+1, each XOR-swizzled) — 16-row span per ds_read_b128.
  auto RD = [&](const uint8_t* base, int rr) -> i32x8 {
    int c0 = g * 2;
    union { i32x4 q[2]; i32x8 o; } u;
    u.q[0] = *(const i32x4*)(base + rr * 128 + ((c0 ^ (rr & 7)) << 4));
    u.q[1] = *(const i32x4*)(base + rr * 128 + (((c0 + 1) ^ (rr & 7)) << 4));
    return u.o;
  };

#define MFMA8(am, bn, cc) \
  __builtin_amdgcn_mfma_scale_f32_16x16x128_f8f6f4((am), (bn), (cc), 0, 0, \
      0, 0x7F7F7F7F, 0, 0x7F7F7F7F)

  // prologue: stage tile 0 into buf 0, drain
#pragma unroll
  for (int it = 0; it < 4; ++it) gload_lds16(Agp + goff[it], lds[0] + lofs[it]);
#pragma unroll
  for (int it = 0; it < 4; ++it) gload_lds16(Bgp + goff[it], lds[0] + 32768 + lofs[it]);
  asm volatile("s_waitcnt vmcnt(0)" ::: "memory");
  __builtin_amdgcn_s_barrier();

  for (int t = 0; t < KT; ++t) {
    const uint8_t* As = lds[t & 1];
    const uint8_t* Bs = lds[t & 1] + 32768;
    uint8_t* Ld = lds[(t + 1) & 1];
    const int kb = (t + 1) << 7;         // next tile's K byte offset (128 B)
    const bool pf = (t + 1 < KT);        // workgroup-uniform

    // issue next tile's staging first — DMA flows under this tile's compute
    if (pf) {
#pragma unroll
      for (int it = 0; it < 4; ++it) gload_lds16(Agp + goff[it] + kb, Ld + lofs[it]);
#pragma unroll
      for (int it = 0; it < 4; ++it) gload_lds16(Bgp + goff[it] + kb, Ld + 32768 + lofs[it]);
    }

    // interleaved reads + MFMA (no mid barriers; compiler schedules lgkmcnt)
    i32x8 af[4], bqa0, bqa1, bqb0, bqb1;
#pragma unroll
    for (int m = 0; m < 4; ++m) af[m] = RD(As, raM[m]);
    bqa0 = RD(Bs, rbN[0]); bqa1 = RD(Bs, rbN[1]);
    bqb0 = RD(Bs, rbN[2]); bqb1 = RD(Bs, rbN[3]);
#pragma unroll
    for (int m = 0; m < 4; ++m) {
      acc[m][0] = MFMA8(af[m], bqa0, acc[m][0]);
      acc[m][1] = MFMA8(af[m], bqa1, acc[m][1]);
    }
    bqa0 = RD(Bs, rbN[4]); bqa1 = RD(Bs, rbN[5]);
#pragma unroll
    for (int m = 0; m < 4; ++m) {
      acc[m][2] = MFMA8(af[m], bqb0, acc[m][2]);
      acc[m][3] = MFMA8(af[m], bqb1, acc[m][3]);
    }
    bqb0 = RD(Bs, rbN[6]); bqb1 = RD(Bs, rbN[7]);
#pragma unroll
    for (int m = 0; m < 4; ++m) {
      acc[m][4] = MFMA8(af[m], bqa0, acc[m][4]);
      acc[m][5] = MFMA8(af[m], bqa1, acc[m][5]);
    }
#pragma unroll
    for (int m = 0; m < 4; ++m) {
      acc[m][6] = MFMA8(af[m], bqb0, acc[m][6]);
      acc[m][7] = MFMA8(af[m], bqb1, acc[m][7]);
    }

    if (pf) asm volatile("s_waitcnt vmcnt(0)" ::: "memory");  // next tile landed
    __builtin_amdgcn_s_barrier();   // buf handoff: all waves done reading/staging
  }

  // ---- epilogue: undo W x64 pre-scale, bias, LSE partial + target grab ----
  const float inv64 = 0.015625f;
  float bv[8];
#pragma unroll
  for (int n = 0; n < 8; ++n) bv[n] = bias[n0 + wn * 128 + n * 16 + li];

  float4* mrg = (float4*)lds[0];   // [256 rows][2 wn] — all vmem drained
#pragma unroll
  for (int m = 0; m < 4; ++m)
#pragma unroll
    for (int i = 0; i < 4; ++i) {
      float x[8];
#pragma unroll
      for (int n = 0; n < 8; ++n) x[n] = acc[m][n][i] * inv64 + bv[n];
      float tmax = x[0];
#pragma unroll
      for (int n = 1; n < 8; ++n) tmax = fmaxf(tmax, x[n]);
#pragma unroll
      for (int d = 1; d <= 8; d <<= 1) tmax = fmaxf(tmax, __shfl_xor(tmax, d));
      float tsum = 0.f;
#pragma unroll
      for (int n = 0; n < 8; ++n) tsum += __expf(x[n] - tmax);
#pragma unroll
      for (int d = 1; d <= 8; d <<= 1) tsum += __shfl_xor(tsum, d);
      int lrow = wm * 64 + m * 16 + g * 4 + i;
      int tv = target[rowbase + lrow];
      int c = ((tv == IGNORE_INDEX) ? 0 : tv) - (n0 + wn * 128);  // in [0,128)?
      float rt = 0.f;
#pragma unroll
      for (int n = 0; n < 8; ++n)
        rt += ((c >> 4) == n && (c & 15) == li) ? x[n] : 0.f;
#pragma unroll
      for (int d = 1; d <= 8; d <<= 1) rt += __shfl_xor(rt, d);
      if (li == 0) mrg[lrow * 2 + wn] = float4{tmax, tsum, rt, 0.f};
    }
  __syncthreads();
  if (tid < BM) {
    float4 p0 = mrg[tid * 2 + 0], p1 = mrg[tid * 2 + 1];
    float mm = fmaxf(p0.x, p1.x);
    float ss = p0.y * __expf(p0.x - mm) + p1.y * __expf(p1.x - mm);
    partials[(size_t)split * kM + rowbase + tid] = float4{mm, ss, p0.z + p1.z, 0.f};
  }
#undef MFMA8
}

// ---------------- combine split partials -> per-token logp ----------------
// one wave per row; 64 lanes strided over splits, shfl LSE-merge. grid = kM/4.
__global__ __launch_bounds__(256) void combine_lse(
    const float4* __restrict__ partials, float* __restrict__ per_tok, int nsplit)
{
  int row  = blockIdx.x * 4 + (threadIdx.x >> 6);
  int lane = threadIdx.x & 63;
  float m = -1e30f, s = 0.f, t = 0.f;
  for (int sp = lane; sp < nsplit; sp += 64) {
    float4 p = partials[(size_t)sp * kM + row];
    t += p.z;
    float nm = fmaxf(m, p.x);
    s = s * __expf(m - nm) + p.y * __expf(p.x - nm);
    m = nm;
  }
#pragma unroll
  for (int d = 1; d < 64; d <<= 1) {
    float mo = __shfl_xor(m, d), so = __shfl_xor(s, d), to = __shfl_xor(t, d);
    float nm = fmaxf(m, mo);
    s = s * __expf(m - nm) + so * __expf(mo - nm);
    m = nm; t += to;
  }
  if (lane == 0) per_tok[row] = t - (m + logf(s));
}

// ---------------- final scalar loss ----------------
__global__ __launch_bounds__(1024) void final_loss(
    const float* __restrict__ per_tok, const int* __restrict__ target, float* __restrict__ out)
{
  __shared__ float redv[16], redc[16];
  __shared__ float ssum[8], scnt[8];
  int t = threadIdx.x;
  int wid = t >> 6, lane = t & 63;
  for (int b = 0; b < 8; ++b) {
    int row = b * 1024 + t;
    float mk = (target[row] != IGNORE_INDEX) ? 1.f : 0.f;
    float v = per_tok[row] * mk;
#pragma unroll
    for (int d = 1; d <= 32; d <<= 1) { v += __shfl_xor(v, d); mk += __shfl_xor(mk, d); }
    if (lane == 0) { redv[wid] = v; redc[wid] = mk; }
    __syncthreads();
    if (t == 0) {
      float sv = 0.f, sc = 0.f;
      for (int j = 0; j < 16; ++j) { sv += redv[j]; sc += redc[j]; }
      ssum[b] = sv; scnt[b] = sc;
    }
    __syncthreads();
  }
  if (t == 0) {
    float nsum = 0.f, ncnt = 0.f;
    for (int b = 0; b < 4; ++b) { nsum += ssum[b]; ncnt += scnt[b]; }
    float nll = -nsum / ncnt;
    float pref = 0.f;
    for (int b = 0; b < 4; ++b) {
      float avc = ssum[b] / scnt[b];
      float avr = ssum[b + 4] / scnt[b + 4];
      float d = 0.1f * (avc - avr);                 // BETA = 0.1
      float ls = (d >= 0.f) ? -log1pf(__expf(-d)) : d - log1pf(__expf(d));
      pref += ls;
    }
    pref *= 0.25f;                                  // mean over 4 pairs
    out[0] = 1.0f * nll - pref;                     // ALPHA = 1.0
  }
}

extern "C" void kernel_launch(void* const* d_in, const int* in_sizes, int n_in,
                              void* d_out, int out_size, void* d_ws, size_t ws_size,
                              hipStream_t stream) {
  const float* lin_weight = (const float*)d_in[0];  // [V][H]
  const float* input      = (const float*)d_in[1];  // [B2][T][H]
  const int*   target     = (const int*)d_in[2];    // [B2][T]
  const float* bias       = (const float*)d_in[3];  // [V]
  float* out = (float*)d_out;

  uint8_t* ws = (uint8_t*)d_ws;
  size_t offW = 0;
  size_t offA = offW + (size_t)kV * kH;                // 65,536,000 B (fp8)
  size_t offP = offA + (size_t)kM * kH;                // +16,777,216 B
  size_t offT = offP + (size_t)NSPLIT * kM * 16;       // +16,384,000 B
  size_t need = offT + (size_t)kM * 4;
  if (ws_size < need) return;  // clean failure signal (output stays 0)

  uint8_t* Wb = ws + offW;
  uint8_t* Ab = ws + offA;
  float4* partials = (float4*)(ws + offP);
  float*  per_tok  = (float*)(ws + offT);

  // W pre-scaled by 64 (escape e4m3 denormals; undone by inv64 in epilogue)
  cast_to_fp8<<<2048, 256, 0, stream>>>(lin_weight, (uint2*)Wb, kV * kH / 8, 64.0f);
  cast_to_fp8<<<1024, 256, 0, stream>>>(input, (uint2*)Ab, kM * kH / 8, 1.0f);
  fused_lse<<<NWG, 512, 0, stream>>>(Wb, Ab, bias, target, partials);
  combine_lse<<<kM / 4, 256, 0, stream>>>(partials, per_tok, NSPLIT);
  final_loss<<<1, 1024, 0, stream>>>(per_tok, target, out);
}